// Round 13
// baseline (433.644 us; speedup 1.0000x reference)
//
#include <hip/hip_runtime.h>
#include <hip/hip_fp16.h>

#define NN 100000
#define NE 1600000
#define NNP (NN + 64)  // row-padded feature buffers (last block reads past NN)

// CSR bucket sort params
#define NPB 512                          // nodes per bucket (bucket = dst>>9)
#define NBUK ((NN + NPB - 1) / NPB)      // 196
#define EPB 2048                         // edges per binA block
#define ABLK ((NE + EPB - 1) / EPB)      // 782
#define BCAP 10240                       // segment capacity (mean 8192, sd ~90)

typedef _Float16 half8 __attribute__((ext_vector_type(8)));
typedef float f32x4 __attribute__((ext_vector_type(4)));

// ---------------- bucketed CSR build (no node-grained global atomics) ----------------

__global__ __launch_bounds__(256) void bucket_init(int* __restrict__ bucket_cur) {
  int t = blockIdx.x * 256 + threadIdx.x;
  if (t < NBUK) bucket_cur[t] = t * BCAP;
}

// pass A: bin edges by dst>>9 into fixed-capacity segments; store packed (src<<9)|local
__global__ __launch_bounds__(256) void binA(const int* __restrict__ src,
                                            const int* __restrict__ dst,
                                            int* __restrict__ bucket_cur,
                                            unsigned* __restrict__ binned) {
  __shared__ int hist[NBUK];
  __shared__ int sc[256];
  __shared__ int lbase[NBUK];
  __shared__ int gbase[NBUK];
  __shared__ int lcur[NBUK];
  __shared__ uint2 stage[EPB];
  int t = threadIdx.x;
  int e0 = blockIdx.x * EPB;
  if (t < NBUK) hist[t] = 0;
  __syncthreads();
  int es[8], ed[8];
#pragma unroll
  for (int j = 0; j < 8; ++j) {
    int e = e0 + t + j * 256;
    if (e < NE) {
      es[j] = src[e];
      ed[j] = dst[e];
      atomicAdd(&hist[ed[j] >> 9], 1);
    } else {
      es[j] = -1;
      ed[j] = 0;
    }
  }
  __syncthreads();
  sc[t] = (t < NBUK) ? hist[t] : 0;
  __syncthreads();
  for (int off = 1; off < 256; off <<= 1) {
    int v = (t >= off) ? sc[t - off] : 0;
    __syncthreads();
    sc[t] += v;
    __syncthreads();
  }
  if (t < NBUK) {
    int h = hist[t];
    int lb = sc[t] - h;
    lbase[t] = lb;
    lcur[t] = lb;
    if (h > 0) gbase[t] = atomicAdd(&bucket_cur[t], h);
  }
  __syncthreads();
#pragma unroll
  for (int j = 0; j < 8; ++j) {
    if (es[j] >= 0) {
      int b = ed[j] >> 9;
      int slot = atomicAdd(&lcur[b], 1);
      stage[slot] = make_uint2((unsigned)es[j], (unsigned)ed[j]);
    }
  }
  __syncthreads();
  int total = min(EPB, NE - e0);
  for (int i = t; i < total; i += 256) {
    uint2 p = stage[i];
    int b = (int)(p.y >> 9);
    binned[(size_t)gbase[b] + (i - lbase[b])] = (p.x << 9) | (p.y & 511u);
  }
}

// scan bucket fill counts -> global bucket bases
__global__ __launch_bounds__(256) void bucket_scan(const int* __restrict__ bucket_cur,
                                                   int* __restrict__ bucket_base,
                                                   int* __restrict__ row_ptr) {
  __shared__ int part[256];
  int t = threadIdx.x;
  int v = (t < NBUK) ? (bucket_cur[t] - t * BCAP) : 0;
  part[t] = v;
  __syncthreads();
  for (int off = 1; off < 256; off <<= 1) {
    int u = (t >= off) ? part[t - off] : 0;
    __syncthreads();
    part[t] += u;
    __syncthreads();
  }
  if (t < NBUK) bucket_base[t] = part[t] - v;
  if (t == 0) row_ptr[NN] = NE;
}

// pass B: per bucket — per-node histogram + scan in LDS, write row_ptr/deg_inv/col coalesced
__global__ __launch_bounds__(256) void binB(const unsigned* __restrict__ binned,
                                            const int* __restrict__ bucket_cur,
                                            const int* __restrict__ bucket_base,
                                            int* __restrict__ row_ptr,
                                            float* __restrict__ deg_inv,
                                            int* __restrict__ col) {
  __shared__ int hist[NPB];
  __shared__ int cur2[NPB];
  __shared__ int part[256];
  __shared__ int srcS[BCAP];
  int b = blockIdx.x;
  int n0 = b * NPB;
  int n1 = min(n0 + NPB, NN);
  int cnt = bucket_cur[b] - b * BCAP;
  int gb = bucket_base[b];
  size_t seg = (size_t)b * BCAP;
  int t = threadIdx.x;
  hist[t] = 0;
  hist[t + 256] = 0;
  __syncthreads();
  for (int i = t; i < cnt; i += 256)
    atomicAdd(&hist[(int)(binned[seg + i] & 511u)], 1);
  __syncthreads();
  int c0 = hist[2 * t], c1 = hist[2 * t + 1];
  int s = c0 + c1;
  part[t] = s;
  __syncthreads();
  for (int off = 1; off < 256; off <<= 1) {
    int u = (t >= off) ? part[t - off] : 0;
    __syncthreads();
    part[t] += u;
    __syncthreads();
  }
  int excl = part[t] - s;
  cur2[2 * t] = excl;
  cur2[2 * t + 1] = excl + c0;
  int n = n0 + 2 * t;
  if (n < n1) {
    row_ptr[n] = gb + excl;
    deg_inv[n] = 1.0f / (float)(c0 > 1 ? c0 : 1);
  }
  if (n + 1 < n1) {
    row_ptr[n + 1] = gb + excl + c0;
    deg_inv[n + 1] = 1.0f / (float)(c1 > 1 ? c1 : 1);
  }
  __syncthreads();
  for (int i = t; i < cnt; i += 256) {
    unsigned p = binned[seg + i];
    int slot = atomicAdd(&cur2[(int)(p & 511u)], 1);
    srcS[slot] = (int)(p >> 9);
  }
  __syncthreads();
  for (int i = t; i < cnt; i += 256) col[(size_t)gb + i] = srcS[i];
}

// ---------------- x -> fp16 shadow ----------------

__global__ __launch_bounds__(256) void tohalf(const float* __restrict__ x,
                                              __half* __restrict__ x16) {
  size_t o = ((size_t)blockIdx.x * 256 + threadIdx.x) * 8;
  float4 a = *(const float4*)(x + o);
  float4 b = *(const float4*)(x + o + 4);
  union { uint4 u; __half h[8]; } U;
  U.h[0] = __float2half(a.x); U.h[1] = __float2half(a.y);
  U.h[2] = __float2half(a.z); U.h[3] = __float2half(a.w);
  U.h[4] = __float2half(b.x); U.h[5] = __float2half(b.y);
  U.h[6] = __float2half(b.z); U.h[7] = __float2half(b.w);
  *(uint4*)(x16 + o) = U.u;
}

// ---------------- weight prep: fp16 transposed B operands ----------------

__global__ __launch_bounds__(256) void prep_weights(const float* __restrict__ Wl,
                                                    const float* __restrict__ Wr,
                                                    const float* __restrict__ Wp,
                                                    _Float16* __restrict__ WcatT,
                                                    _Float16* __restrict__ WpT) {
  int t = blockIdx.x * 256 + threadIdx.x;
  if (t < 4 * 64 * 128) {
    int l = t >> 13, rem = t & 8191, j = rem >> 7, k = rem & 127;
    float v = (k < 64) ? Wl[l * 4096 + k * 64 + j] : Wr[l * 4096 + (k - 64) * 64 + j];
    WcatT[t] = (_Float16)v;
  }
  if (t < 4 * 32 * 64) {
    int l = t >> 11, rem = t & 2047, j = rem >> 6, k = rem & 63;
    WpT[t] = (_Float16)Wp[(size_t)(l * 64 + k) * 32 + j];
  }
}

// ---------------- fused layer: gather-mean (LDS) + MFMA GEMM + projection ----------------
// 64 nodes / 512-thread block (8 waves -> 12500 waves total, ~100% occupancy cap).
// Phase 1: wave w gathers nodes w*8..w*8+7 (lane = feature) -> aggS.
// Phase 2: wave w owns row-tile w>>1, col-half w&1 of hn = [aggS|h]@[Wl;Wr]+bl;
//          proj: wave w owns row-tile w>>1, col-tile w&1 of out (+)= hn@Wp.
// mfma_f32_16x16x32_f16: A row=lane&15, k=(lane>>4)*8+i ; B col=lane&15 same k ;
// D col=lane&15, row=(lane>>4)*4+reg.  flags bit0: layer0; bit1: write hn16.

#define PADA 72  // row stride (halves): 144B rows, 16B-aligned half8 reads
#define PADC 72

__global__ __launch_bounds__(512, 8) void fused_layer(
    const _Float16* __restrict__ h16,
    const int* __restrict__ row_ptr, const int* __restrict__ col,
    const float* __restrict__ deginv,
    const _Float16* __restrict__ WcatT, const float* __restrict__ bl,
    const _Float16* __restrict__ WpT, const float* __restrict__ bp,
    _Float16* __restrict__ hn16, float* __restrict__ out, int flags) {
  __shared__ _Float16 aggS[64 * PADA];
  __shared__ _Float16 cS[64 * PADC];
  int tid = threadIdx.x;
  int w = tid >> 6, l = tid & 63;
  int base = blockIdx.x * 64;

  // ---- phase 1: gather-mean, wave per node (lane = feature), 8 nodes/wave ----
  for (int i = 0; i < 8; ++i) {
    int n = base + (w << 3) + i;
    float acc = 0.f;
    if (n < NN) {
      int beg = row_ptr[n], end = row_ptr[n + 1];
      int e = beg;
      while (e < end) {
        int chunk = end - e;
        if (chunk > 64) chunk = 64;
        int cv = col[e + (l < chunk ? l : chunk - 1)];
        int q = 0;
        for (; q + 8 <= chunk; q += 8) {
          int s0 = __shfl(cv, q + 0, 64), s1 = __shfl(cv, q + 1, 64);
          int s2 = __shfl(cv, q + 2, 64), s3 = __shfl(cv, q + 3, 64);
          int s4 = __shfl(cv, q + 4, 64), s5 = __shfl(cv, q + 5, 64);
          int s6 = __shfl(cv, q + 6, 64), s7 = __shfl(cv, q + 7, 64);
          float v0 = (float)h16[(size_t)s0 * 64 + l];
          float v1 = (float)h16[(size_t)s1 * 64 + l];
          float v2 = (float)h16[(size_t)s2 * 64 + l];
          float v3 = (float)h16[(size_t)s3 * 64 + l];
          float v4 = (float)h16[(size_t)s4 * 64 + l];
          float v5 = (float)h16[(size_t)s5 * 64 + l];
          float v6 = (float)h16[(size_t)s6 * 64 + l];
          float v7 = (float)h16[(size_t)s7 * 64 + l];
          acc += ((v0 + v1) + (v2 + v3)) + ((v4 + v5) + (v6 + v7));
        }
        for (; q < chunk; ++q) {
          int s = __shfl(cv, q, 64);
          acc += (float)h16[(size_t)s * 64 + l];
        }
        e += chunk;
      }
      acc *= deginv[n];
    }
    aggS[((w << 3) + i) * PADA + l] = (_Float16)acc;
  }
  __syncthreads();

  // ---- phase 2: MFMA GEMM (wave: row-tile rt = w>>1, col-half ch = w&1) ----
  int lr = l & 15, lg = l >> 4;
  int rt = w >> 1, ch = w & 1;
  int arow = base + (rt << 4) + lr;

  f32x4 acc4[2];
#pragma unroll
  for (int cc = 0; cc < 2; ++cc) {
    int ct = ch * 2 + cc;
    float b = bl[ct * 16 + lr];
    acc4[cc] = (f32x4){b, b, b, b};
  }
  const half8 a0 = *(const half8*)(aggS + ((rt << 4) + lr) * PADA + lg * 8);
  const half8 a1 = *(const half8*)(aggS + ((rt << 4) + lr) * PADA + 32 + lg * 8);
  const half8 a2 = *(const half8*)(h16 + (size_t)arow * 64 + lg * 8);
  const half8 a3 = *(const half8*)(h16 + (size_t)arow * 64 + 32 + lg * 8);
#pragma unroll
  for (int cc = 0; cc < 2; ++cc) {
    int ct = ch * 2 + cc;
    const _Float16* wb = WcatT + (ct * 16 + lr) * 128 + lg * 8;
    half8 b0 = *(const half8*)(wb);
    half8 b1 = *(const half8*)(wb + 32);
    half8 b2 = *(const half8*)(wb + 64);
    half8 b3 = *(const half8*)(wb + 96);
    acc4[cc] = __builtin_amdgcn_mfma_f32_16x16x32_f16(a0, b0, acc4[cc], 0, 0, 0);
    acc4[cc] = __builtin_amdgcn_mfma_f32_16x16x32_f16(a1, b1, acc4[cc], 0, 0, 0);
    acc4[cc] = __builtin_amdgcn_mfma_f32_16x16x32_f16(a2, b2, acc4[cc], 0, 0, 0);
    acc4[cc] = __builtin_amdgcn_mfma_f32_16x16x32_f16(a3, b3, acc4[cc], 0, 0, 0);
  }

  // stage hn tile to LDS (fp16): D-layout scatter
#pragma unroll
  for (int cc = 0; cc < 2; ++cc) {
    int ct = ch * 2 + cc;
#pragma unroll
    for (int r = 0; r < 4; ++r)
      cS[((rt << 4) + (lg << 2) + r) * PADC + ct * 16 + lr] = (_Float16)acc4[cc][r];
  }
  __syncthreads();

  // coalesced hn16 write from LDS (skipped on last layer)
  if (flags & 2) {
    int row = tid >> 3, c8 = (tid & 7) * 8;
    *(half8*)(hn16 + (size_t)(base + row) * 64 + c8) =
        *(const half8*)(cS + row * PADC + c8);
  }

  // projection: out(64x32) (+)= C(64x64) @ Wp(64x32); wave: row-tile rt, col-tile ch
  int colo = ch * 16 + lr;
  f32x4 pacc;
  if (flags & 1) {
    float b = bp[colo];
    pacc = (f32x4){b, b, b, b};
  } else {
#pragma unroll
    for (int r = 0; r < 4; ++r) {
      int row = base + (rt << 4) + (lg << 2) + r;
      pacc[r] = (row < NN) ? out[(size_t)row * 32 + colo] : 0.f;
    }
  }
  const _Float16* crow = cS + ((rt << 4) + lr) * PADC + lg * 8;
  half8 c0 = *(const half8*)(crow);
  half8 c1 = *(const half8*)(crow + 32);
  const _Float16* wp = WpT + colo * 64 + lg * 8;
  half8 w0 = *(const half8*)(wp);
  half8 w1 = *(const half8*)(wp + 32);
  pacc = __builtin_amdgcn_mfma_f32_16x16x32_f16(c0, w0, pacc, 0, 0, 0);
  pacc = __builtin_amdgcn_mfma_f32_16x16x32_f16(c1, w1, pacc, 0, 0, 0);
#pragma unroll
  for (int r = 0; r < 4; ++r) {
    int row = base + (rt << 4) + (lg << 2) + r;
    if (row < NN) out[(size_t)row * 32 + colo] = pacc[r];
  }
}

// ---------------- launch ----------------

extern "C" void kernel_launch(void* const* d_in, const int* in_sizes, int n_in,
                              void* d_out, int out_size, void* d_ws, size_t ws_size,
                              hipStream_t stream) {
  const float* x  = (const float*)d_in[0];
  const int*   ei = (const int*)d_in[1];   // [2, NE] int32
  const float* Wl = (const float*)d_in[2];
  const float* bl = (const float*)d_in[3];
  const float* Wr = (const float*)d_in[4];
  const float* Wp = (const float*)d_in[5];
  const float* bp = (const float*)d_in[6];
  float* out = (float*)d_out;

  char* ws = (char*)d_ws;
  size_t off = 0;
  auto alloc = [&](size_t bytes) {
    void* p = ws + off;
    off = (off + bytes + 255) & ~(size_t)255;
    return p;
  };
  int*      row_ptr     = (int*)alloc(((size_t)NN + 1) * 4);
  float*    deginv      = (float*)alloc((size_t)NN * 4);
  int*      col         = (int*)alloc((size_t)NE * 4);
  int*      bucket_cur  = (int*)alloc((size_t)NBUK * 4);
  int*      bucket_base = (int*)alloc((size_t)NBUK * 4);
  unsigned* binned      = (unsigned*)alloc((size_t)NBUK * BCAP * 4);
  __half*   x16         = (__half*)alloc((size_t)NNP * 64 * 2);
  __half*   h16A        = (__half*)alloc((size_t)NNP * 64 * 2);
  __half*   h16B        = (__half*)alloc((size_t)NNP * 64 * 2);
  _Float16* WcatT       = (_Float16*)alloc((size_t)4 * 64 * 128 * 2);
  _Float16* WpT         = (_Float16*)alloc((size_t)4 * 32 * 64 * 2);

  tohalf<<<3125, 256, 0, stream>>>(x, x16);
  prep_weights<<<128, 256, 0, stream>>>(Wl, Wr, Wp, WcatT, WpT);
  bucket_init<<<1, 256, 0, stream>>>(bucket_cur);
  binA<<<ABLK, 256, 0, stream>>>(ei, ei + NE, bucket_cur, binned);
  bucket_scan<<<1, 256, 0, stream>>>(bucket_cur, bucket_base, row_ptr);
  binB<<<NBUK, 256, 0, stream>>>(binned, bucket_cur, bucket_base, row_ptr, deginv, col);

  const __half* cur16 = x16;
  __half* bufs[2] = {h16A, h16B};
  int nblk = (NN + 63) / 64;  // 1563
  for (int l = 0; l < 4; ++l) {
    __half* nxt = bufs[l & 1];
    int flags = (l == 0 ? 1 : 0) | (l < 3 ? 2 : 0);
    fused_layer<<<nblk, 512, 0, stream>>>(
        (const _Float16*)cur16, row_ptr, col, deginv,
        WcatT + l * 8192, bl + l * 64, WpT + l * 2048, bp,
        (_Float16*)nxt, out, flags);
    cur16 = nxt;
  }
}

// Round 14
// 375.359 us; speedup vs baseline: 1.1553x; 1.1553x over previous
//
#include <hip/hip_runtime.h>
#include <hip/hip_fp16.h>

#define NN 100000
#define NE 1600000
#define NNP (NN + 64)  // row-padded feature buffers (last block reads past NN)

// CSR bucket sort params
#define NPB 512                          // nodes per bucket (bucket = dst>>9)
#define NBUK ((NN + NPB - 1) / NPB)      // 196
#define EPB 2048                         // edges per binA block
#define ABLK ((NE + EPB - 1) / EPB)      // 782
#define BCAP 10240                       // segment capacity (mean 8192, sd ~90)

typedef _Float16 half8 __attribute__((ext_vector_type(8)));
typedef float f32x4 __attribute__((ext_vector_type(4)));

// ---------------- bucketed CSR build (no node-grained global atomics) ----------------

__global__ __launch_bounds__(256) void bucket_init(int* __restrict__ bucket_cur) {
  int t = blockIdx.x * 256 + threadIdx.x;
  if (t < NBUK) bucket_cur[t] = t * BCAP;
}

// pass A: bin edges by dst>>9 into fixed-capacity segments; store packed (src<<9)|local
__global__ __launch_bounds__(256) void binA(const int* __restrict__ src,
                                            const int* __restrict__ dst,
                                            int* __restrict__ bucket_cur,
                                            unsigned* __restrict__ binned) {
  __shared__ int hist[NBUK];
  __shared__ int sc[256];
  __shared__ int lbase[NBUK];
  __shared__ int gbase[NBUK];
  __shared__ int lcur[NBUK];
  __shared__ uint2 stage[EPB];
  int t = threadIdx.x;
  int e0 = blockIdx.x * EPB;
  if (t < NBUK) hist[t] = 0;
  __syncthreads();
  int es[8], ed[8];
#pragma unroll
  for (int j = 0; j < 8; ++j) {
    int e = e0 + t + j * 256;
    if (e < NE) {
      es[j] = src[e];
      ed[j] = dst[e];
      atomicAdd(&hist[ed[j] >> 9], 1);
    } else {
      es[j] = -1;
      ed[j] = 0;
    }
  }
  __syncthreads();
  sc[t] = (t < NBUK) ? hist[t] : 0;
  __syncthreads();
  for (int off = 1; off < 256; off <<= 1) {
    int v = (t >= off) ? sc[t - off] : 0;
    __syncthreads();
    sc[t] += v;
    __syncthreads();
  }
  if (t < NBUK) {
    int h = hist[t];
    int lb = sc[t] - h;
    lbase[t] = lb;
    lcur[t] = lb;
    if (h > 0) gbase[t] = atomicAdd(&bucket_cur[t], h);
  }
  __syncthreads();
#pragma unroll
  for (int j = 0; j < 8; ++j) {
    if (es[j] >= 0) {
      int b = ed[j] >> 9;
      int slot = atomicAdd(&lcur[b], 1);
      stage[slot] = make_uint2((unsigned)es[j], (unsigned)ed[j]);
    }
  }
  __syncthreads();
  int total = min(EPB, NE - e0);
  for (int i = t; i < total; i += 256) {
    uint2 p = stage[i];
    int b = (int)(p.y >> 9);
    binned[(size_t)gbase[b] + (i - lbase[b])] = (p.x << 9) | (p.y & 511u);
  }
}

// scan bucket fill counts -> global bucket bases
__global__ __launch_bounds__(256) void bucket_scan(const int* __restrict__ bucket_cur,
                                                   int* __restrict__ bucket_base,
                                                   int* __restrict__ row_ptr) {
  __shared__ int part[256];
  int t = threadIdx.x;
  int v = (t < NBUK) ? (bucket_cur[t] - t * BCAP) : 0;
  part[t] = v;
  __syncthreads();
  for (int off = 1; off < 256; off <<= 1) {
    int u = (t >= off) ? part[t - off] : 0;
    __syncthreads();
    part[t] += u;
    __syncthreads();
  }
  if (t < NBUK) bucket_base[t] = part[t] - v;
  if (t == 0) row_ptr[NN] = NE;
}

// pass B: per bucket — per-node histogram + scan in LDS, write row_ptr/deg_inv/col coalesced
__global__ __launch_bounds__(256) void binB(const unsigned* __restrict__ binned,
                                            const int* __restrict__ bucket_cur,
                                            const int* __restrict__ bucket_base,
                                            int* __restrict__ row_ptr,
                                            float* __restrict__ deg_inv,
                                            int* __restrict__ col) {
  __shared__ int hist[NPB];
  __shared__ int cur2[NPB];
  __shared__ int part[256];
  __shared__ int srcS[BCAP];
  int b = blockIdx.x;
  int n0 = b * NPB;
  int n1 = min(n0 + NPB, NN);
  int cnt = bucket_cur[b] - b * BCAP;
  int gb = bucket_base[b];
  size_t seg = (size_t)b * BCAP;
  int t = threadIdx.x;
  hist[t] = 0;
  hist[t + 256] = 0;
  __syncthreads();
  for (int i = t; i < cnt; i += 256)
    atomicAdd(&hist[(int)(binned[seg + i] & 511u)], 1);
  __syncthreads();
  int c0 = hist[2 * t], c1 = hist[2 * t + 1];
  int s = c0 + c1;
  part[t] = s;
  __syncthreads();
  for (int off = 1; off < 256; off <<= 1) {
    int u = (t >= off) ? part[t - off] : 0;
    __syncthreads();
    part[t] += u;
    __syncthreads();
  }
  int excl = part[t] - s;
  cur2[2 * t] = excl;
  cur2[2 * t + 1] = excl + c0;
  int n = n0 + 2 * t;
  if (n < n1) {
    row_ptr[n] = gb + excl;
    deg_inv[n] = 1.0f / (float)(c0 > 1 ? c0 : 1);
  }
  if (n + 1 < n1) {
    row_ptr[n + 1] = gb + excl + c0;
    deg_inv[n + 1] = 1.0f / (float)(c1 > 1 ? c1 : 1);
  }
  __syncthreads();
  for (int i = t; i < cnt; i += 256) {
    unsigned p = binned[seg + i];
    int slot = atomicAdd(&cur2[(int)(p & 511u)], 1);
    srcS[slot] = (int)(p >> 9);
  }
  __syncthreads();
  for (int i = t; i < cnt; i += 256) col[(size_t)gb + i] = srcS[i];
}

// ---------------- x -> fp16 shadow ----------------

__global__ __launch_bounds__(256) void tohalf(const float* __restrict__ x,
                                              __half* __restrict__ x16) {
  size_t o = ((size_t)blockIdx.x * 256 + threadIdx.x) * 8;
  float4 a = *(const float4*)(x + o);
  float4 b = *(const float4*)(x + o + 4);
  union { uint4 u; __half h[8]; } U;
  U.h[0] = __float2half(a.x); U.h[1] = __float2half(a.y);
  U.h[2] = __float2half(a.z); U.h[3] = __float2half(a.w);
  U.h[4] = __float2half(b.x); U.h[5] = __float2half(b.y);
  U.h[6] = __float2half(b.z); U.h[7] = __float2half(b.w);
  *(uint4*)(x16 + o) = U.u;
}

// ---------------- weight prep: fp16 transposed B operands ----------------

__global__ __launch_bounds__(256) void prep_weights(const float* __restrict__ Wl,
                                                    const float* __restrict__ Wr,
                                                    const float* __restrict__ Wp,
                                                    _Float16* __restrict__ WcatT,
                                                    _Float16* __restrict__ WpT) {
  int t = blockIdx.x * 256 + threadIdx.x;
  if (t < 4 * 64 * 128) {
    int l = t >> 13, rem = t & 8191, j = rem >> 7, k = rem & 127;
    float v = (k < 64) ? Wl[l * 4096 + k * 64 + j] : Wr[l * 4096 + (k - 64) * 64 + j];
    WcatT[t] = (_Float16)v;
  }
  if (t < 4 * 32 * 64) {
    int l = t >> 11, rem = t & 2047, j = rem >> 6, k = rem & 63;
    WpT[t] = (_Float16)Wp[(size_t)(l * 64 + k) * 32 + j];
  }
}

// ---------------- fused layer: gather-mean (LDS) + MFMA GEMM + projection ----------------
// 64 nodes / 256-thread block (4 waves), 16 nodes per wave.
// Gather inner loop: uint2/lane (8B), 16 lanes per row -> 4 rows PER wave-instruction;
// lane l handles row l>>4 of each 4-edge group, features 4*(l&15)..+3 (fp32 acc).
// Node epilogue: shfl_xor(16,32) folds row-classes; lanes 0-15 write half8 row to aggS.
// MFMA phase as round 12. flags bit0: layer0 (init out with bp); bit1: write hn16.

#define PADA 72  // row stride (halves): 144B rows, 16B-aligned
#define PADC 72

__global__ __launch_bounds__(256, 4) void fused_layer(
    const _Float16* __restrict__ h16,
    const int* __restrict__ row_ptr, const int* __restrict__ col,
    const float* __restrict__ deginv,
    const _Float16* __restrict__ WcatT, const float* __restrict__ bl,
    const _Float16* __restrict__ WpT, const float* __restrict__ bp,
    _Float16* __restrict__ hn16, float* __restrict__ out, int flags) {
  __shared__ _Float16 aggS[64 * PADA];
  __shared__ _Float16 cS[64 * PADC];
  int tid = threadIdx.x;
  int w = tid >> 6, l = tid & 63;
  int base = blockIdx.x * 64;
  int r4 = l >> 4;          // row-class within 4-edge group
  int fq = (l & 15) * 4;    // feature quad base

  // ---- phase 1: gather-mean ----
  for (int i = 0; i < 16; ++i) {
    int n = base + (w << 4) + i;
    f32x4 acc = (f32x4){0.f, 0.f, 0.f, 0.f};
    if (n < NN) {
      int beg = row_ptr[n], end = row_ptr[n + 1];
      int e = beg;
      while (e < end) {
        int chunk = end - e;
        if (chunk > 64) chunk = 64;
        int cv = col[e + (l < chunk ? l : chunk - 1)];
        int full = chunk & ~3;
        int q = 0;
        for (; q + 16 <= full; q += 16) {  // 4 rows x 4 groups in flight
          int s0 = __shfl(cv, q + r4, 64);
          int s1 = __shfl(cv, q + 4 + r4, 64);
          int s2 = __shfl(cv, q + 8 + r4, 64);
          int s3 = __shfl(cv, q + 12 + r4, 64);
          uint2 v0 = *(const uint2*)(h16 + (size_t)s0 * 64 + fq);
          uint2 v1 = *(const uint2*)(h16 + (size_t)s1 * 64 + fq);
          uint2 v2 = *(const uint2*)(h16 + (size_t)s2 * 64 + fq);
          uint2 v3 = *(const uint2*)(h16 + (size_t)s3 * 64 + fq);
          float2 a0 = __half22float2(*(__half2*)&v0.x), b0 = __half22float2(*(__half2*)&v0.y);
          float2 a1 = __half22float2(*(__half2*)&v1.x), b1 = __half22float2(*(__half2*)&v1.y);
          float2 a2 = __half22float2(*(__half2*)&v2.x), b2 = __half22float2(*(__half2*)&v2.y);
          float2 a3 = __half22float2(*(__half2*)&v3.x), b3 = __half22float2(*(__half2*)&v3.y);
          acc[0] += (a0.x + a1.x) + (a2.x + a3.x);
          acc[1] += (a0.y + a1.y) + (a2.y + a3.y);
          acc[2] += (b0.x + b1.x) + (b2.x + b3.x);
          acc[3] += (b0.y + b1.y) + (b2.y + b3.y);
        }
        for (; q + 4 <= full; q += 4) {    // single 4-edge group
          int s = __shfl(cv, q + r4, 64);
          uint2 v = *(const uint2*)(h16 + (size_t)s * 64 + fq);
          float2 a = __half22float2(*(__half2*)&v.x), b = __half22float2(*(__half2*)&v.y);
          acc[0] += a.x; acc[1] += a.y; acc[2] += b.x; acc[3] += b.y;
        }
        if (q < chunk) {                   // 1-3 edges: predicated group
          int qq = q + r4;
          int s = __shfl(cv, qq < chunk ? qq : chunk - 1, 64);
          uint2 v = *(const uint2*)(h16 + (size_t)s * 64 + fq);
          if (qq < chunk) {
            float2 a = __half22float2(*(__half2*)&v.x), b = __half22float2(*(__half2*)&v.y);
            acc[0] += a.x; acc[1] += a.y; acc[2] += b.x; acc[3] += b.y;
          }
        }
        e += chunk;
      }
    }
    // fold the 4 row-classes
#pragma unroll
    for (int k = 0; k < 4; ++k) {
      acc[k] += __shfl_xor(acc[k], 16, 64);
      acc[k] += __shfl_xor(acc[k], 32, 64);
    }
    if (l < 16 && n < NN) {
      float di = deginv[n];
      union { uint2 u; __half2 h2[2]; } P;
      P.h2[0] = __floats2half2_rn(acc[0] * di, acc[1] * di);
      P.h2[1] = __floats2half2_rn(acc[2] * di, acc[3] * di);
      *(uint2*)(aggS + ((w << 4) + i) * PADA + l * 4) = P.u;
    } else if (l < 16) {
      *(uint2*)(aggS + ((w << 4) + i) * PADA + l * 4) = make_uint2(0u, 0u);
    }
  }
  __syncthreads();

  // ---- phase 2: MFMA GEMM (wave w owns rows w*16..w*16+15, all 4 col-tiles) ----
  int lr = l & 15, lg = l >> 4;
  int arow = base + (w << 4) + lr;

  f32x4 acc4[4];
#pragma unroll
  for (int ct = 0; ct < 4; ++ct) {
    float b = bl[ct * 16 + lr];
    acc4[ct] = (f32x4){b, b, b, b};
  }
  const half8 a0 = *(const half8*)(aggS + ((w << 4) + lr) * PADA + lg * 8);
  const half8 a1 = *(const half8*)(aggS + ((w << 4) + lr) * PADA + 32 + lg * 8);
  const half8 a2 = *(const half8*)(h16 + (size_t)arow * 64 + lg * 8);
  const half8 a3 = *(const half8*)(h16 + (size_t)arow * 64 + 32 + lg * 8);
#pragma unroll
  for (int ct = 0; ct < 4; ++ct) {
    const _Float16* wb = WcatT + (ct * 16 + lr) * 128 + lg * 8;
    half8 b0 = *(const half8*)(wb);
    half8 b1 = *(const half8*)(wb + 32);
    half8 b2 = *(const half8*)(wb + 64);
    half8 b3 = *(const half8*)(wb + 96);
    acc4[ct] = __builtin_amdgcn_mfma_f32_16x16x32_f16(a0, b0, acc4[ct], 0, 0, 0);
    acc4[ct] = __builtin_amdgcn_mfma_f32_16x16x32_f16(a1, b1, acc4[ct], 0, 0, 0);
    acc4[ct] = __builtin_amdgcn_mfma_f32_16x16x32_f16(a2, b2, acc4[ct], 0, 0, 0);
    acc4[ct] = __builtin_amdgcn_mfma_f32_16x16x32_f16(a3, b3, acc4[ct], 0, 0, 0);
  }

  // stage hn tile to LDS (fp16): D-layout scatter
#pragma unroll
  for (int ct = 0; ct < 4; ++ct)
#pragma unroll
    for (int r = 0; r < 4; ++r)
      cS[((w << 4) + (lg << 2) + r) * PADC + ct * 16 + lr] = (_Float16)acc4[ct][r];
  __syncthreads();

  // coalesced hn16 write from LDS (skipped on last layer)
  if (flags & 2) {
#pragma unroll
    for (int j = 0; j < 2; ++j) {
      int idx = tid + j * 256;
      int row = idx >> 3, c8 = (idx & 7) * 8;
      *(half8*)(hn16 + (size_t)(base + row) * 64 + c8) =
          *(const half8*)(cS + row * PADC + c8);
    }
  }

  // projection: out(64x32) (+)= C(64x64) @ Wp(64x32)
  f32x4 pacc[2];
#pragma unroll
  for (int pt = 0; pt < 2; ++pt) {
    int colo = pt * 16 + lr;
    if (flags & 1) {
      float b = bp[colo];
      pacc[pt] = (f32x4){b, b, b, b};
    } else {
#pragma unroll
      for (int r = 0; r < 4; ++r) {
        int row = base + (w << 4) + (lg << 2) + r;
        pacc[pt][r] = (row < NN) ? out[(size_t)row * 32 + colo] : 0.f;
      }
    }
  }
  const _Float16* crow = cS + ((w << 4) + lr) * PADC + lg * 8;
  half8 c0 = *(const half8*)(crow);
  half8 c1 = *(const half8*)(crow + 32);
#pragma unroll
  for (int pt = 0; pt < 2; ++pt) {
    const _Float16* wp = WpT + (pt * 16 + lr) * 64 + lg * 8;
    half8 w0 = *(const half8*)(wp);
    half8 w1 = *(const half8*)(wp + 32);
    pacc[pt] = __builtin_amdgcn_mfma_f32_16x16x32_f16(c0, w0, pacc[pt], 0, 0, 0);
    pacc[pt] = __builtin_amdgcn_mfma_f32_16x16x32_f16(c1, w1, pacc[pt], 0, 0, 0);
  }
#pragma unroll
  for (int pt = 0; pt < 2; ++pt) {
    int colo = pt * 16 + lr;
#pragma unroll
    for (int r = 0; r < 4; ++r) {
      int row = base + (w << 4) + (lg << 2) + r;
      if (row < NN) out[(size_t)row * 32 + colo] = pacc[pt][r];
    }
  }
}

// ---------------- launch ----------------

extern "C" void kernel_launch(void* const* d_in, const int* in_sizes, int n_in,
                              void* d_out, int out_size, void* d_ws, size_t ws_size,
                              hipStream_t stream) {
  const float* x  = (const float*)d_in[0];
  const int*   ei = (const int*)d_in[1];   // [2, NE] int32
  const float* Wl = (const float*)d_in[2];
  const float* bl = (const float*)d_in[3];
  const float* Wr = (const float*)d_in[4];
  const float* Wp = (const float*)d_in[5];
  const float* bp = (const float*)d_in[6];
  float* out = (float*)d_out;

  char* ws = (char*)d_ws;
  size_t off = 0;
  auto alloc = [&](size_t bytes) {
    void* p = ws + off;
    off = (off + bytes + 255) & ~(size_t)255;
    return p;
  };
  int*      row_ptr     = (int*)alloc(((size_t)NN + 1) * 4);
  float*    deginv      = (float*)alloc((size_t)NN * 4);
  int*      col         = (int*)alloc((size_t)NE * 4);
  int*      bucket_cur  = (int*)alloc((size_t)NBUK * 4);
  int*      bucket_base = (int*)alloc((size_t)NBUK * 4);
  unsigned* binned      = (unsigned*)alloc((size_t)NBUK * BCAP * 4);
  __half*   x16         = (__half*)alloc((size_t)NNP * 64 * 2);
  __half*   h16A        = (__half*)alloc((size_t)NNP * 64 * 2);
  __half*   h16B        = (__half*)alloc((size_t)NNP * 64 * 2);
  _Float16* WcatT       = (_Float16*)alloc((size_t)4 * 64 * 128 * 2);
  _Float16* WpT         = (_Float16*)alloc((size_t)4 * 32 * 64 * 2);

  tohalf<<<3125, 256, 0, stream>>>(x, x16);
  prep_weights<<<128, 256, 0, stream>>>(Wl, Wr, Wp, WcatT, WpT);
  bucket_init<<<1, 256, 0, stream>>>(bucket_cur);
  binA<<<ABLK, 256, 0, stream>>>(ei, ei + NE, bucket_cur, binned);
  bucket_scan<<<1, 256, 0, stream>>>(bucket_cur, bucket_base, row_ptr);
  binB<<<NBUK, 256, 0, stream>>>(binned, bucket_cur, bucket_base, row_ptr, deginv, col);

  const __half* cur16 = x16;
  __half* bufs[2] = {h16A, h16B};
  int nblk = (NN + 63) / 64;  // 1563
  for (int l = 0; l < 4; ++l) {
    __half* nxt = bufs[l & 1];
    int flags = (l == 0 ? 1 : 0) | (l < 3 ? 2 : 0);
    fused_layer<<<nblk, 256, 0, stream>>>(
        (const _Float16*)cur16, row_ptr, col, deginv,
        WcatT + l * 8192, bl + l * 64, WpT + l * 2048, bp,
        (_Float16*)nxt, out, flags);
    cur16 = nxt;
  }
}